// Round 1
// baseline (1250.853 us; speedup 1.0000x reference)
//
#include <hip/hip_runtime.h>

#define N_NODES   20000
#define N_EDGES   200000
#define NODE_DIM  32
#define EDGE_DIM  16
#define HIDDEN    32
#define N_GRAPHS  64

// ---------------------------------------------------------------------------
// Edge kernel: one lane = one edge. Fully fused NNConv message computation:
//   h   = relu(ea @ W1 + b1)                      (recomputed per-k, uniform W1 in SGPRs)
//   msg = x[src] @ reshape(h @ W2 + b2, 32, 32)   (k runtime loop, i/o unrolled)
//   atomicAdd(agg[tgt], msg); atomicAdd(cnt[tgt], 1)
// W1/W2/b1/b2 accesses are wave-uniform -> compiler emits s_load (weights in SGPRs).
// ---------------------------------------------------------------------------
__global__ __launch_bounds__(256) void edge_conv_kernel(
    const float* __restrict__ feat,   // [N][32]
    const float* __restrict__ ea,     // [E][16]
    const int*   __restrict__ srcs,   // [E]
    const int*   __restrict__ tgts,   // [E]
    const float* __restrict__ W1,     // [16][32]
    const float* __restrict__ b1,     // [32]
    const float* __restrict__ W2,     // [32][1024]
    const float* __restrict__ b2,     // [1024]
    float*       __restrict__ agg,    // [N][32]  (atomic accumulate)
    float*       __restrict__ cnt)    // [N] or null
{
    int e = blockIdx.x * blockDim.x + threadIdx.x;
    if (e >= N_EDGES) return;

    // edge attributes -> registers (vectorized)
    float a[EDGE_DIM];
    const float4* ea4 = reinterpret_cast<const float4*>(ea + (size_t)e * EDGE_DIM);
    #pragma unroll
    for (int q = 0; q < EDGE_DIM / 4; ++q) {
        float4 t = ea4[q];
        a[q*4+0] = t.x; a[q*4+1] = t.y; a[q*4+2] = t.z; a[q*4+3] = t.w;
    }

    // source node features -> registers (vectorized)
    int s = srcs[e];
    float x[32];
    const float4* x4 = reinterpret_cast<const float4*>(feat + (size_t)s * 32);
    #pragma unroll
    for (int q = 0; q < 8; ++q) {
        float4 t = x4[q];
        x[q*4+0] = t.x; x[q*4+1] = t.y; x[q*4+2] = t.z; x[q*4+3] = t.w;
    }

    float acc[32];
    #pragma unroll
    for (int o = 0; o < 32; ++o) acc[o] = 0.0f;

    // b2 contribution: acc[o] += sum_i x_i * b2[i*32+o]
    #pragma unroll
    for (int i = 0; i < 32; ++i) {
        float xi = x[i];
        #pragma unroll
        for (int o = 0; o < 32; ++o) acc[o] += xi * b2[i*32+o];
    }

    // main contraction: acc[o] += h_k * x_i * W2[k][i*32+o]
    // k is a runtime (wave-uniform) loop; h_k recomputed from a[] (i/o fully unrolled,
    // so x[] and acc[] stay in registers -- no runtime-indexed arrays).
    for (int k = 0; k < 32; ++k) {
        float hk = b1[k];
        #pragma unroll
        for (int j = 0; j < EDGE_DIM; ++j) hk += a[j] * W1[j*32 + k];
        hk = fmaxf(hk, 0.0f);
        const float* w = W2 + (size_t)k * 1024;
        #pragma unroll
        for (int i = 0; i < 32; ++i) {
            float c = hk * x[i];
            #pragma unroll
            for (int o = 0; o < 32; ++o) acc[o] += c * w[i*32+o];
        }
    }

    int t = tgts[e];
    float* dst = agg + (size_t)t * 32;
    #pragma unroll
    for (int o = 0; o < 32; ++o) atomicAdd(dst + o, acc[o]);
    if (cnt) atomicAdd(cnt + t, 1.0f);
}

// ---------------------------------------------------------------------------
// Node kernel: h_out = relu(agg/max(cnt,1) + feat @ root + bias)
// Optionally fuses global mean-pool accumulation (for the second conv).
// ---------------------------------------------------------------------------
__global__ __launch_bounds__(256) void node_update_kernel(
    const float* __restrict__ feat,   // [N][32]
    const float* __restrict__ agg,    // [N][32]
    const float* __restrict__ cnt,    // [N]
    const float* __restrict__ root,   // [32][32]
    const float* __restrict__ bias,   // [32]
    float*       __restrict__ outf,   // [N][32] or null
    const int*   __restrict__ batch,  // [N] or null
    float*       __restrict__ pool,   // [G][32] (atomic) when batch != null
    float*       __restrict__ pcnt)   // [G]     (atomic) when batch != null
{
    int v = blockIdx.x * blockDim.x + threadIdx.x;
    if (v >= N_NODES) return;

    float x[32];
    const float4* x4 = reinterpret_cast<const float4*>(feat + (size_t)v * 32);
    #pragma unroll
    for (int q = 0; q < 8; ++q) {
        float4 t = x4[q];
        x[q*4+0] = t.x; x[q*4+1] = t.y; x[q*4+2] = t.z; x[q*4+3] = t.w;
    }

    float inv = 1.0f / fmaxf(cnt[v], 1.0f);

    float acc[32];
    const float4* g4 = reinterpret_cast<const float4*>(agg + (size_t)v * 32);
    #pragma unroll
    for (int q = 0; q < 8; ++q) {
        float4 t = g4[q];
        acc[q*4+0] = t.x * inv + bias[q*4+0];
        acc[q*4+1] = t.y * inv + bias[q*4+1];
        acc[q*4+2] = t.z * inv + bias[q*4+2];
        acc[q*4+3] = t.w * inv + bias[q*4+3];
    }

    #pragma unroll
    for (int i = 0; i < 32; ++i) {
        float xi = x[i];
        #pragma unroll
        for (int o = 0; o < 32; ++o) acc[o] += xi * root[i*32+o];
    }

    #pragma unroll
    for (int o = 0; o < 32; ++o) acc[o] = fmaxf(acc[o], 0.0f);

    if (outf) {
        float4* o4 = reinterpret_cast<float4*>(outf + (size_t)v * 32);
        #pragma unroll
        for (int q = 0; q < 8; ++q) {
            float4 t;
            t.x = acc[q*4+0]; t.y = acc[q*4+1]; t.z = acc[q*4+2]; t.w = acc[q*4+3];
            o4[q] = t;
        }
    }

    if (batch) {
        int g = batch[v];
        float* p = pool + (size_t)g * 32;
        #pragma unroll
        for (int o = 0; o < 32; ++o) atomicAdd(p + o, acc[o]);
        atomicAdd(pcnt + g, 1.0f);
    }
}

// ---------------------------------------------------------------------------
// Head: out[g] = (pool[g]/max(pcnt[g],1)) @ fc_W + fc_b   -> [64][2]
// ---------------------------------------------------------------------------
__global__ void head_kernel(
    const float* __restrict__ pool,   // [G][32]
    const float* __restrict__ pcnt,   // [G]
    const float* __restrict__ fcW,    // [32][2]
    const float* __restrict__ fcb,    // [2]
    float*       __restrict__ out)    // [G][2]
{
    int g = threadIdx.x;
    if (g >= N_GRAPHS) return;
    float inv = 1.0f / fmaxf(pcnt[g], 1.0f);
    float o0 = fcb[0], o1 = fcb[1];
    #pragma unroll
    for (int i = 0; i < 32; ++i) {
        float m = pool[g*32+i] * inv;
        o0 += m * fcW[i*2+0];
        o1 += m * fcW[i*2+1];
    }
    out[g*2+0] = o0;
    out[g*2+1] = o1;
}

extern "C" void kernel_launch(void* const* d_in, const int* in_sizes, int n_in,
                              void* d_out, int out_size, void* d_ws, size_t ws_size,
                              hipStream_t stream)
{
    const float* x      = (const float*)d_in[0];
    const float* ea     = (const float*)d_in[1];
    const int*   ei     = (const int*)d_in[2];   // [2][E]
    const int*   batch  = (const int*)d_in[3];
    const float* en1_W1 = (const float*)d_in[4];
    const float* en1_b1 = (const float*)d_in[5];
    const float* en1_W2 = (const float*)d_in[6];
    const float* en1_b2 = (const float*)d_in[7];
    const float* root1  = (const float*)d_in[8];
    const float* bias1  = (const float*)d_in[9];
    const float* en2_W1 = (const float*)d_in[10];
    const float* en2_b1 = (const float*)d_in[11];
    const float* en2_W2 = (const float*)d_in[12];
    const float* en2_b2 = (const float*)d_in[13];
    const float* root2  = (const float*)d_in[14];
    const float* bias2  = (const float*)d_in[15];
    const float* fcW    = (const float*)d_in[16];
    const float* fcb    = (const float*)d_in[17];

    const int* srcs = ei;
    const int* tgts = ei + N_EDGES;

    // workspace layout (floats); zero-needed regions first, one memset covers them
    float* f    = (float*)d_ws;
    float* agg1 = f;                                   // N*32
    float* agg2 = agg1 + (size_t)N_NODES * 32;         // N*32
    float* cnt  = agg2 + (size_t)N_NODES * 32;         // N
    float* pool = cnt  + N_NODES;                      // G*32
    float* pcnt = pool + (size_t)N_GRAPHS * 32;        // G
    float* h1   = pcnt + N_GRAPHS;                     // N*32 (fully overwritten)
    size_t zeroBytes = ((size_t)N_NODES*32*2 + N_NODES + N_GRAPHS*32 + N_GRAPHS) * sizeof(float);

    hipMemsetAsync(d_ws, 0, zeroBytes, stream);

    dim3 eb(256), eg((N_EDGES + 255) / 256);
    dim3 nb(256), ng((N_NODES + 255) / 256);

    // conv1
    edge_conv_kernel<<<eg, eb, 0, stream>>>(x, ea, srcs, tgts,
                                            en1_W1, en1_b1, en1_W2, en1_b2,
                                            agg1, cnt);
    node_update_kernel<<<ng, nb, 0, stream>>>(x, agg1, cnt, root1, bias1,
                                              h1, nullptr, nullptr, nullptr);
    // conv2 (counts reused)
    edge_conv_kernel<<<eg, eb, 0, stream>>>(h1, ea, srcs, tgts,
                                            en2_W1, en2_b1, en2_W2, en2_b2,
                                            agg2, nullptr);
    node_update_kernel<<<ng, nb, 0, stream>>>(h1, agg2, cnt, root2, bias2,
                                              nullptr, batch, pool, pcnt);
    // output head
    head_kernel<<<dim3(1), dim3(64), 0, stream>>>(pool, pcnt, fcW, fcb, (float*)d_out);
}

// Round 2
// 594.304 us; speedup vs baseline: 2.1047x; 2.1047x over previous
//
#include <hip/hip_runtime.h>

#define N_NODES   20000
#define N_EDGES   200000
#define NODE_DIM  32
#define EDGE_DIM  16
#define HIDDEN    32
#define N_GRAPHS  64

// ===========================================================================
// CSR-path kernels (no float atomics on the hot path)
// ===========================================================================

__global__ __launch_bounds__(256) void build_deg_kernel(
    const int* __restrict__ tgts, int* __restrict__ deg)
{
    int e = blockIdx.x * blockDim.x + threadIdx.x;
    if (e >= N_EDGES) return;
    atomicAdd(deg + tgts[e], 1);
}

// single-block chunked exclusive scan over 20000 degrees
__global__ __launch_bounds__(256) void scan_deg_kernel(
    const int* __restrict__ deg, int* __restrict__ start, int* __restrict__ cursor)
{
    __shared__ int partial[256];
    const int C = (N_NODES + 255) / 256;   // 79
    int t  = threadIdx.x;
    int lo = t * C;
    int hi = lo + C < N_NODES ? lo + C : N_NODES;
    int s = 0;
    for (int i = lo; i < hi; ++i) s += deg[i];
    partial[t] = s;
    __syncthreads();
    if (t == 0) {
        int run = 0;
        for (int i = 0; i < 256; ++i) { int v = partial[i]; partial[i] = run; run += v; }
    }
    __syncthreads();
    int run = partial[t];
    for (int i = lo; i < hi; ++i) {
        start[i]  = run;
        cursor[i] = run;
        run += deg[i];
    }
    if (lo < N_NODES && hi == N_NODES) start[N_NODES] = run;
}

__global__ __launch_bounds__(256) void scatter_edges_kernel(
    const int* __restrict__ tgts, int* __restrict__ cursor, int* __restrict__ eid)
{
    int e = blockIdx.x * blockDim.x + threadIdx.x;
    if (e >= N_EDGES) return;
    int pos = atomicAdd(cursor + tgts[e], 1);
    eid[pos] = e;
}

// One lane = one edge. Fully fused NNConv message, coalesced float4 store.
// W1/W2/b1/b2 accesses are wave-uniform -> scalar loads (weights via SGPRs).
__global__ __launch_bounds__(256) void edge_msg_kernel(
    const float* __restrict__ feat,   // [N][32]
    const float* __restrict__ ea,     // [E][16]
    const int*   __restrict__ srcs,   // [E]
    const float* __restrict__ W1,     // [16][32]
    const float* __restrict__ b1,     // [32]
    const float* __restrict__ W2,     // [32][1024]
    const float* __restrict__ b2,     // [1024]
    float*       __restrict__ msg)    // [E][32]
{
    int e = blockIdx.x * blockDim.x + threadIdx.x;
    if (e >= N_EDGES) return;

    float a[EDGE_DIM];
    const float4* ea4 = reinterpret_cast<const float4*>(ea + (size_t)e * EDGE_DIM);
    #pragma unroll
    for (int q = 0; q < EDGE_DIM / 4; ++q) {
        float4 t = ea4[q];
        a[q*4+0] = t.x; a[q*4+1] = t.y; a[q*4+2] = t.z; a[q*4+3] = t.w;
    }

    int s = srcs[e];
    float x[32];
    const float4* x4 = reinterpret_cast<const float4*>(feat + (size_t)s * 32);
    #pragma unroll
    for (int q = 0; q < 8; ++q) {
        float4 t = x4[q];
        x[q*4+0] = t.x; x[q*4+1] = t.y; x[q*4+2] = t.z; x[q*4+3] = t.w;
    }

    float acc[32];
    #pragma unroll
    for (int o = 0; o < 32; ++o) acc[o] = 0.0f;

    // b2 term: acc[o] += sum_i x_i * b2[i*32+o]
    #pragma unroll
    for (int i = 0; i < 32; ++i) {
        float xi = x[i];
        #pragma unroll
        for (int o = 0; o < 32; ++o) acc[o] += xi * b2[i*32+o];
    }

    // main contraction: acc[o] += h_k * x_i * W2[k][i*32+o]
    for (int k = 0; k < 32; ++k) {
        float hk = b1[k];
        #pragma unroll
        for (int j = 0; j < EDGE_DIM; ++j) hk += a[j] * W1[j*32 + k];
        hk = fmaxf(hk, 0.0f);
        const float* w = W2 + (size_t)k * 1024;
        #pragma unroll
        for (int i = 0; i < 32; ++i) {
            float c = hk * x[i];
            #pragma unroll
            for (int o = 0; o < 32; ++o) acc[o] += c * w[i*32+o];
        }
    }

    float4* m4 = reinterpret_cast<float4*>(msg + (size_t)e * 32);
    #pragma unroll
    for (int q = 0; q < 8; ++q) {
        float4 t;
        t.x = acc[q*4+0]; t.y = acc[q*4+1]; t.z = acc[q*4+2]; t.w = acc[q*4+3];
        m4[q] = t;
    }
}

// 32 lanes per node; lane o owns output channel o.
// agg = mean over incident msgs; out = relu(agg + feat@root + bias).
// Optionally accumulates global mean-pool (tiny atomics on 64 graphs).
__global__ __launch_bounds__(256) void gather_update_kernel(
    const float* __restrict__ feat,   // [N][32]
    const float* __restrict__ msg,    // [E][32]
    const int*   __restrict__ start,  // [N+1]
    const int*   __restrict__ eid,    // [E]
    const float* __restrict__ root,   // [32][32]
    const float* __restrict__ bias,   // [32]
    float*       __restrict__ outf,   // [N][32] or null
    const int*   __restrict__ batch,  // [N] or null
    float*       __restrict__ pool,   // [G][32]
    float*       __restrict__ pcnt)   // [G]
{
    int idx = blockIdx.x * blockDim.x + threadIdx.x;
    int v = idx >> 5;
    int o = idx & 31;
    if (v >= N_NODES) return;

    int s0 = start[v], s1 = start[v + 1];
    float sum = 0.0f;
    for (int j = s0; j < s1; ++j) {
        int e = eid[j];                       // uniform within node group
        sum += msg[(size_t)e * 32 + o];       // coalesced 128B per group
    }
    int d = s1 - s0;
    float acc = sum / (float)(d > 0 ? d : 1) + bias[o];

    const float* xv = feat + (size_t)v * 32;
    #pragma unroll
    for (int i = 0; i < 32; ++i) acc += xv[i] * root[i*32 + o];
    acc = fmaxf(acc, 0.0f);

    if (outf) outf[(size_t)v * 32 + o] = acc;
    if (batch) {
        int g = batch[v];
        atomicAdd(pool + (size_t)g * 32 + o, acc);
        if (o == 0) atomicAdd(pcnt + g, 1.0f);
    }
}

__global__ void head_kernel(
    const float* __restrict__ pool, const float* __restrict__ pcnt,
    const float* __restrict__ fcW, const float* __restrict__ fcb,
    float* __restrict__ out)
{
    int g = threadIdx.x;
    if (g >= N_GRAPHS) return;
    float inv = 1.0f / fmaxf(pcnt[g], 1.0f);
    float o0 = fcb[0], o1 = fcb[1];
    #pragma unroll
    for (int i = 0; i < 32; ++i) {
        float m = pool[g*32 + i] * inv;
        o0 += m * fcW[i*2 + 0];
        o1 += m * fcW[i*2 + 1];
    }
    out[g*2 + 0] = o0;
    out[g*2 + 1] = o1;
}

// ===========================================================================
// Fallback path (round-1 atomic version) if ws_size is too small for CSR
// ===========================================================================

__global__ __launch_bounds__(256) void edge_conv_atomic_kernel(
    const float* __restrict__ feat, const float* __restrict__ ea,
    const int* __restrict__ srcs, const int* __restrict__ tgts,
    const float* __restrict__ W1, const float* __restrict__ b1,
    const float* __restrict__ W2, const float* __restrict__ b2,
    float* __restrict__ agg, float* __restrict__ cnt)
{
    int e = blockIdx.x * blockDim.x + threadIdx.x;
    if (e >= N_EDGES) return;
    float a[EDGE_DIM];
    const float4* ea4 = reinterpret_cast<const float4*>(ea + (size_t)e * EDGE_DIM);
    #pragma unroll
    for (int q = 0; q < EDGE_DIM / 4; ++q) {
        float4 t = ea4[q];
        a[q*4+0] = t.x; a[q*4+1] = t.y; a[q*4+2] = t.z; a[q*4+3] = t.w;
    }
    int s = srcs[e];
    float x[32];
    const float4* x4 = reinterpret_cast<const float4*>(feat + (size_t)s * 32);
    #pragma unroll
    for (int q = 0; q < 8; ++q) {
        float4 t = x4[q];
        x[q*4+0] = t.x; x[q*4+1] = t.y; x[q*4+2] = t.z; x[q*4+3] = t.w;
    }
    float acc[32];
    #pragma unroll
    for (int o = 0; o < 32; ++o) acc[o] = 0.0f;
    #pragma unroll
    for (int i = 0; i < 32; ++i) {
        float xi = x[i];
        #pragma unroll
        for (int o = 0; o < 32; ++o) acc[o] += xi * b2[i*32+o];
    }
    for (int k = 0; k < 32; ++k) {
        float hk = b1[k];
        #pragma unroll
        for (int j = 0; j < EDGE_DIM; ++j) hk += a[j] * W1[j*32 + k];
        hk = fmaxf(hk, 0.0f);
        const float* w = W2 + (size_t)k * 1024;
        #pragma unroll
        for (int i = 0; i < 32; ++i) {
            float c = hk * x[i];
            #pragma unroll
            for (int o = 0; o < 32; ++o) acc[o] += c * w[i*32+o];
        }
    }
    int t = tgts[e];
    float* dst = agg + (size_t)t * 32;
    #pragma unroll
    for (int o = 0; o < 32; ++o) atomicAdd(dst + o, acc[o]);
    if (cnt) atomicAdd(cnt + t, 1.0f);
}

__global__ __launch_bounds__(256) void node_update_kernel(
    const float* __restrict__ feat, const float* __restrict__ agg,
    const float* __restrict__ cnt, const float* __restrict__ root,
    const float* __restrict__ bias, float* __restrict__ outf,
    const int* __restrict__ batch, float* __restrict__ pool,
    float* __restrict__ pcnt)
{
    int v = blockIdx.x * blockDim.x + threadIdx.x;
    if (v >= N_NODES) return;
    float x[32];
    const float4* x4 = reinterpret_cast<const float4*>(feat + (size_t)v * 32);
    #pragma unroll
    for (int q = 0; q < 8; ++q) {
        float4 t = x4[q];
        x[q*4+0] = t.x; x[q*4+1] = t.y; x[q*4+2] = t.z; x[q*4+3] = t.w;
    }
    float inv = 1.0f / fmaxf(cnt[v], 1.0f);
    float acc[32];
    const float4* g4 = reinterpret_cast<const float4*>(agg + (size_t)v * 32);
    #pragma unroll
    for (int q = 0; q < 8; ++q) {
        float4 t = g4[q];
        acc[q*4+0] = t.x * inv + bias[q*4+0];
        acc[q*4+1] = t.y * inv + bias[q*4+1];
        acc[q*4+2] = t.z * inv + bias[q*4+2];
        acc[q*4+3] = t.w * inv + bias[q*4+3];
    }
    #pragma unroll
    for (int i = 0; i < 32; ++i) {
        float xi = x[i];
        #pragma unroll
        for (int o = 0; o < 32; ++o) acc[o] += xi * root[i*32+o];
    }
    #pragma unroll
    for (int o = 0; o < 32; ++o) acc[o] = fmaxf(acc[o], 0.0f);
    if (outf) {
        float4* o4 = reinterpret_cast<float4*>(outf + (size_t)v * 32);
        #pragma unroll
        for (int q = 0; q < 8; ++q) {
            float4 t;
            t.x = acc[q*4+0]; t.y = acc[q*4+1]; t.z = acc[q*4+2]; t.w = acc[q*4+3];
            o4[q] = t;
        }
    }
    if (batch) {
        int g = batch[v];
        float* p = pool + (size_t)g * 32;
        #pragma unroll
        for (int o = 0; o < 32; ++o) atomicAdd(p + o, acc[o]);
        atomicAdd(pcnt + g, 1.0f);
    }
}

// ===========================================================================

extern "C" void kernel_launch(void* const* d_in, const int* in_sizes, int n_in,
                              void* d_out, int out_size, void* d_ws, size_t ws_size,
                              hipStream_t stream)
{
    const float* x      = (const float*)d_in[0];
    const float* ea     = (const float*)d_in[1];
    const int*   ei     = (const int*)d_in[2];   // [2][E]
    const int*   batch  = (const int*)d_in[3];
    const float* en1_W1 = (const float*)d_in[4];
    const float* en1_b1 = (const float*)d_in[5];
    const float* en1_W2 = (const float*)d_in[6];
    const float* en1_b2 = (const float*)d_in[7];
    const float* root1  = (const float*)d_in[8];
    const float* bias1  = (const float*)d_in[9];
    const float* en2_W1 = (const float*)d_in[10];
    const float* en2_b1 = (const float*)d_in[11];
    const float* en2_W2 = (const float*)d_in[12];
    const float* en2_b2 = (const float*)d_in[13];
    const float* root2  = (const float*)d_in[14];
    const float* bias2  = (const float*)d_in[15];
    const float* fcW    = (const float*)d_in[16];
    const float* fcb    = (const float*)d_in[17];

    const int* srcs = ei;
    const int* tgts = ei + N_EDGES;

    dim3 eb(256), eg((N_EDGES + 255) / 256);
    dim3 gb(256), gg((N_NODES * 32 + 255) / 256);

    // ---- CSR path workspace layout (words) ----
    // [deg N][pool G*32][pcnt G]  <- zeroed in one memset
    // [start N+1][cursor N][eid E][msg E*32][h1 N*32]
    size_t need = (size_t)N_NODES + N_GRAPHS*32 + N_GRAPHS
                + (N_NODES + 1) + N_NODES + N_EDGES
                + (size_t)N_EDGES*32 + (size_t)N_NODES*32;

    if (ws_size >= need * sizeof(float)) {
        int*   deg    = (int*)d_ws;
        float* pool   = (float*)(deg + N_NODES);
        float* pcnt   = pool + (size_t)N_GRAPHS*32;
        int*   start  = (int*)(pcnt + N_GRAPHS);
        int*   cursor = start + (N_NODES + 1);
        int*   eid    = cursor + N_NODES;
        float* msg    = (float*)(eid + N_EDGES);
        float* h1     = msg + (size_t)N_EDGES*32;
        size_t zeroBytes = ((size_t)N_NODES + N_GRAPHS*32 + N_GRAPHS) * sizeof(float);

        hipMemsetAsync(d_ws, 0, zeroBytes, stream);

        // CSR build (graph identical for both convs)
        build_deg_kernel<<<eg, eb, 0, stream>>>(tgts, deg);
        scan_deg_kernel<<<dim3(1), dim3(256), 0, stream>>>(deg, start, cursor);
        scatter_edges_kernel<<<eg, eb, 0, stream>>>(tgts, cursor, eid);

        // conv1
        edge_msg_kernel<<<eg, eb, 0, stream>>>(x, ea, srcs,
                                               en1_W1, en1_b1, en1_W2, en1_b2, msg);
        gather_update_kernel<<<gg, gb, 0, stream>>>(x, msg, start, eid, root1, bias1,
                                                    h1, nullptr, nullptr, nullptr);
        // conv2
        edge_msg_kernel<<<eg, eb, 0, stream>>>(h1, ea, srcs,
                                               en2_W1, en2_b1, en2_W2, en2_b2, msg);
        gather_update_kernel<<<gg, gb, 0, stream>>>(h1, msg, start, eid, root2, bias2,
                                                    nullptr, batch, pool, pcnt);

        head_kernel<<<dim3(1), dim3(64), 0, stream>>>(pool, pcnt, fcW, fcb, (float*)d_out);
    } else {
        // fallback: round-1 atomic path
        float* f    = (float*)d_ws;
        float* agg1 = f;
        float* agg2 = agg1 + (size_t)N_NODES * 32;
        float* cnt  = agg2 + (size_t)N_NODES * 32;
        float* pool = cnt  + N_NODES;
        float* pcnt = pool + (size_t)N_GRAPHS * 32;
        float* h1   = pcnt + N_GRAPHS;
        size_t zeroBytes = ((size_t)N_NODES*32*2 + N_NODES + N_GRAPHS*32 + N_GRAPHS) * sizeof(float);

        hipMemsetAsync(d_ws, 0, zeroBytes, stream);

        dim3 nb(256), ng((N_NODES + 255) / 256);
        edge_conv_atomic_kernel<<<eg, eb, 0, stream>>>(x, ea, srcs, tgts,
                                                en1_W1, en1_b1, en1_W2, en1_b2, agg1, cnt);
        node_update_kernel<<<ng, nb, 0, stream>>>(x, agg1, cnt, root1, bias1,
                                                  h1, nullptr, nullptr, nullptr);
        edge_conv_atomic_kernel<<<eg, eb, 0, stream>>>(h1, ea, srcs, tgts,
                                                en2_W1, en2_b1, en2_W2, en2_b2, agg2, nullptr);
        node_update_kernel<<<ng, nb, 0, stream>>>(h1, agg2, cnt, root2, bias2,
                                                  nullptr, batch, pool, pcnt);
        head_kernel<<<dim3(1), dim3(64), 0, stream>>>(pool, pcnt, fcW, fcb, (float*)d_out);
    }
}

// Round 3
// 498.250 us; speedup vs baseline: 2.5105x; 1.1928x over previous
//
#include <hip/hip_runtime.h>

#define N_NODES   20000
#define N_EDGES   200000
#define NODE_DIM  32
#define EDGE_DIM  16
#define HIDDEN    32
#define N_GRAPHS  64
#define T_NODES   15   // src nodes per block; LDS = 15*1024*4 + 15*32*4*2 = 65280 B <= 64KB

// ===========================================================================
// CSR build (both tgt-CSR and src-CSR in fused passes)
// ===========================================================================

__global__ __launch_bounds__(256) void build_deg2_kernel(
    const int* __restrict__ tgts, const int* __restrict__ srcs,
    int* __restrict__ deg_t, int* __restrict__ deg_s)
{
    int e = blockIdx.x * blockDim.x + threadIdx.x;
    if (e >= N_EDGES) return;
    atomicAdd(deg_t + tgts[e], 1);
    atomicAdd(deg_s + srcs[e], 1);
}

__device__ void chunked_scan(const int* __restrict__ deg, int* __restrict__ start,
                             int* __restrict__ cursor, int* partial)
{
    const int C = (N_NODES + 255) / 256;   // 79
    int t  = threadIdx.x;
    int lo = t * C;
    int hi = lo + C < N_NODES ? lo + C : N_NODES;
    int s = 0;
    for (int i = lo; i < hi; ++i) s += deg[i];
    partial[t] = s;
    __syncthreads();
    if (t == 0) {
        int run = 0;
        for (int i = 0; i < 256; ++i) { int v = partial[i]; partial[i] = run; run += v; }
    }
    __syncthreads();
    int run = partial[t];
    for (int i = lo; i < hi; ++i) {
        start[i]  = run;
        cursor[i] = run;
        run += deg[i];
    }
    if (lo < N_NODES && hi == N_NODES) start[N_NODES] = run;
    __syncthreads();
}

__global__ __launch_bounds__(256) void scan2_kernel(
    const int* __restrict__ deg_t, int* __restrict__ start_t, int* __restrict__ cur_t,
    const int* __restrict__ deg_s, int* __restrict__ start_s, int* __restrict__ cur_s)
{
    __shared__ int partial[256];
    chunked_scan(deg_t, start_t, cur_t, partial);
    chunked_scan(deg_s, start_s, cur_s, partial);
}

__global__ __launch_bounds__(256) void scatter2_kernel(
    const int* __restrict__ tgts, const int* __restrict__ srcs,
    int* __restrict__ cur_t, int* __restrict__ cur_s,
    int* __restrict__ eid_t, int* __restrict__ eid_s)
{
    int e = blockIdx.x * blockDim.x + threadIdx.x;
    if (e >= N_EDGES) return;
    int p1 = atomicAdd(cur_t + tgts[e], 1);
    eid_t[p1] = e;
    int p2 = atomicAdd(cur_s + srcs[e], 1);
    eid_s[p2] = e;
}

// ===========================================================================
// src_conv: per block, T_NODES src nodes.
// Phase A: P[t][k][o] = sum_i x[t][i]*W2[k][i*32+o]; Q[t][o] = sum_i x[t][i]*b2[i*32+o]
//          (W2 read once per block, coalesced float4; x staged in LDS, broadcast)
// Phase B: for each out-edge e of the tile: h_k = relu(b1+ea@W1) per lane-k,
//          msg[e][o] = Q[s][o] + sum_k shfl(h,k) * P[s][k][o]   (LDS conflict-free)
// ===========================================================================
__global__ __launch_bounds__(256, 2) void src_conv_kernel(
    const float* __restrict__ feat,     // [N][32]
    const float* __restrict__ ea,       // [E][16]
    const int*   __restrict__ srcs,     // [E]
    const int*   __restrict__ start_s,  // [N+1]
    const int*   __restrict__ eid_s,    // [E]
    const float* __restrict__ W1,       // [16][32]
    const float* __restrict__ b1,       // [32]
    const float* __restrict__ W2,       // [32][1024]
    const float* __restrict__ b2,       // [1024]
    float*       __restrict__ msg)      // [E][32]
{
    __shared__ float P[T_NODES][32][32];   // 61440 B
    __shared__ float Q[T_NODES][32];       //  1920 B
    __shared__ float XT[T_NODES][32];      //  1920 B

    int tid = threadIdx.x;
    int v0  = blockIdx.x * T_NODES;
    int T_act = (N_NODES - v0) < T_NODES ? (N_NODES - v0) : T_NODES;

    // ---- stage x tile into LDS (clamped for tail block) ----
    if (tid < 8 * T_NODES) {
        int t  = tid >> 3;
        int og = tid & 7;
        int vv = v0 + t; if (vv > N_NODES - 1) vv = N_NODES - 1;
        float4 xx = *reinterpret_cast<const float4*>(feat + (size_t)vv * 32 + og * 4);
        *reinterpret_cast<float4*>(&XT[t][og * 4]) = xx;
    }
    __syncthreads();

    // ---- Phase A: P tile ----
    {
        int og = tid & 7;     // o = og*4 + c
        int k  = tid >> 3;    // 0..31
        float acc[T_NODES][4];
        #pragma unroll
        for (int t = 0; t < T_NODES; ++t) {
            acc[t][0] = 0.f; acc[t][1] = 0.f; acc[t][2] = 0.f; acc[t][3] = 0.f;
        }
        const float* w2p = W2 + (size_t)k * 1024 + og * 4;
        #pragma unroll
        for (int i = 0; i < 32; ++i) {
            float4 w4 = *reinterpret_cast<const float4*>(w2p + i * 32);
            #pragma unroll
            for (int t = 0; t < T_NODES; ++t) {
                float xv = XT[t][i];
                acc[t][0] += xv * w4.x; acc[t][1] += xv * w4.y;
                acc[t][2] += xv * w4.z; acc[t][3] += xv * w4.w;
            }
        }
        #pragma unroll
        for (int t = 0; t < T_NODES; ++t) {
            float4 w; w.x = acc[t][0]; w.y = acc[t][1]; w.z = acc[t][2]; w.w = acc[t][3];
            *reinterpret_cast<float4*>(&P[t][k][og * 4]) = w;
        }
    }
    // ---- Q tile (threads 0..119) ----
    if (tid < 8 * T_NODES) {
        int t  = tid >> 3;
        int og = tid & 7;
        float q0 = 0.f, q1 = 0.f, q2 = 0.f, q3 = 0.f;
        const float* b2p = b2 + og * 4;
        #pragma unroll
        for (int i = 0; i < 32; ++i) {
            float4 b4 = *reinterpret_cast<const float4*>(b2p + i * 32);
            float xv = XT[t][i];
            q0 += xv * b4.x; q1 += xv * b4.y; q2 += xv * b4.z; q3 += xv * b4.w;
        }
        float4 qq; qq.x = q0; qq.y = q1; qq.z = q2; qq.w = q3;
        *reinterpret_cast<float4*>(&Q[t][og * 4]) = qq;
    }
    __syncthreads();

    // ---- Phase B: edges of this tile (contiguous src-CSR slice) ----
    int jb = start_s[v0];
    int je = start_s[v0 + T_act];
    int slot = tid >> 5;          // 0..7 (8 edges in flight per block iter)
    int kl   = tid & 31;          // lane's k (for h) and o (for output)
    int half = tid & 32;          // base lane of my 32-group within the wave

    // hoist W1 column + b1 (reused for every edge)
    float w1c[EDGE_DIM];
    #pragma unroll
    for (int j = 0; j < EDGE_DIM; ++j) w1c[j] = W1[j * 32 + kl];
    float b1v = b1[kl];

    for (int j0 = jb; j0 < je; j0 += 8) {
        int j = j0 + slot;
        if (j < je) {
            int e  = eid_s[j];
            int sl = srcs[e] - v0;
            const float4* ea4 = reinterpret_cast<const float4*>(ea + (size_t)e * EDGE_DIM);
            float4 a0 = ea4[0], a1 = ea4[1], a2 = ea4[2], a3 = ea4[3];
            float hv = b1v;
            hv += a0.x * w1c[0]  + a0.y * w1c[1]  + a0.z * w1c[2]  + a0.w * w1c[3];
            hv += a1.x * w1c[4]  + a1.y * w1c[5]  + a1.z * w1c[6]  + a1.w * w1c[7];
            hv += a2.x * w1c[8]  + a2.y * w1c[9]  + a2.z * w1c[10] + a2.w * w1c[11];
            hv += a3.x * w1c[12] + a3.y * w1c[13] + a3.z * w1c[14] + a3.w * w1c[15];
            float h = fmaxf(hv, 0.f);

            float accv = Q[sl][kl];
            #pragma unroll
            for (int k = 0; k < 32; ++k) {
                float hk = __shfl(h, half + k, 64);   // broadcast within my 32-group
                accv += hk * P[sl][k][kl];            // lanes o=0..31 -> banks 0..31
            }
            msg[(size_t)e * 32 + kl] = accv;
        }
    }
}

// ===========================================================================
// gather_update: 32 lanes per node (lane o = channel o), tgt-CSR mean,
// + root GEMM + bias + relu; optional global mean-pool accumulation.
// ===========================================================================
__global__ __launch_bounds__(256) void gather_update_kernel(
    const float* __restrict__ feat,   // [N][32]
    const float* __restrict__ msg,    // [E][32]
    const int*   __restrict__ start,  // [N+1] (tgt)
    const int*   __restrict__ eid,    // [E]
    const float* __restrict__ root,   // [32][32]
    const float* __restrict__ bias,   // [32]
    float*       __restrict__ outf,   // [N][32] or null
    const int*   __restrict__ batch,  // [N] or null
    float*       __restrict__ pool,   // [G][32]
    float*       __restrict__ pcnt)   // [G]
{
    int idx = blockIdx.x * blockDim.x + threadIdx.x;
    int v = idx >> 5;
    int o = idx & 31;
    if (v >= N_NODES) return;

    int s0 = start[v], s1 = start[v + 1];
    float sum = 0.0f;
    for (int j = s0; j < s1; ++j) {
        int e = eid[j];
        sum += msg[(size_t)e * 32 + o];
    }
    int d = s1 - s0;
    float acc = sum / (float)(d > 0 ? d : 1) + bias[o];

    const float* xv = feat + (size_t)v * 32;
    #pragma unroll
    for (int i = 0; i < 32; ++i) acc += xv[i] * root[i * 32 + o];
    acc = fmaxf(acc, 0.0f);

    if (outf) outf[(size_t)v * 32 + o] = acc;
    if (batch) {
        int g = batch[v];
        atomicAdd(pool + (size_t)g * 32 + o, acc);
        if (o == 0) atomicAdd(pcnt + g, 1.0f);
    }
}

__global__ void head_kernel(
    const float* __restrict__ pool, const float* __restrict__ pcnt,
    const float* __restrict__ fcW, const float* __restrict__ fcb,
    float* __restrict__ out)
{
    int g = threadIdx.x;
    if (g >= N_GRAPHS) return;
    float inv = 1.0f / fmaxf(pcnt[g], 1.0f);
    float o0 = fcb[0], o1 = fcb[1];
    #pragma unroll
    for (int i = 0; i < 32; ++i) {
        float m = pool[g * 32 + i] * inv;
        o0 += m * fcW[i * 2 + 0];
        o1 += m * fcW[i * 2 + 1];
    }
    out[g * 2 + 0] = o0;
    out[g * 2 + 1] = o1;
}

// ===========================================================================
// Fallback (round-2 proven path): per-edge fused kernel, tgt-CSR only
// ===========================================================================
__global__ __launch_bounds__(256) void build_deg_kernel(
    const int* __restrict__ tgts, int* __restrict__ deg)
{
    int e = blockIdx.x * blockDim.x + threadIdx.x;
    if (e >= N_EDGES) return;
    atomicAdd(deg + tgts[e], 1);
}

__global__ __launch_bounds__(256) void scan_deg_kernel(
    const int* __restrict__ deg, int* __restrict__ start, int* __restrict__ cursor)
{
    __shared__ int partial[256];
    chunked_scan(deg, start, cursor, partial);
}

__global__ __launch_bounds__(256) void scatter_edges_kernel(
    const int* __restrict__ tgts, int* __restrict__ cursor, int* __restrict__ eid)
{
    int e = blockIdx.x * blockDim.x + threadIdx.x;
    if (e >= N_EDGES) return;
    int pos = atomicAdd(cursor + tgts[e], 1);
    eid[pos] = e;
}

__global__ __launch_bounds__(256) void edge_msg_kernel(
    const float* __restrict__ feat, const float* __restrict__ ea,
    const int* __restrict__ srcs,
    const float* __restrict__ W1, const float* __restrict__ b1,
    const float* __restrict__ W2, const float* __restrict__ b2,
    float* __restrict__ msg)
{
    int e = blockIdx.x * blockDim.x + threadIdx.x;
    if (e >= N_EDGES) return;
    float a[EDGE_DIM];
    const float4* ea4 = reinterpret_cast<const float4*>(ea + (size_t)e * EDGE_DIM);
    #pragma unroll
    for (int q = 0; q < EDGE_DIM / 4; ++q) {
        float4 t = ea4[q];
        a[q*4+0] = t.x; a[q*4+1] = t.y; a[q*4+2] = t.z; a[q*4+3] = t.w;
    }
    int s = srcs[e];
    float x[32];
    const float4* x4 = reinterpret_cast<const float4*>(feat + (size_t)s * 32);
    #pragma unroll
    for (int q = 0; q < 8; ++q) {
        float4 t = x4[q];
        x[q*4+0] = t.x; x[q*4+1] = t.y; x[q*4+2] = t.z; x[q*4+3] = t.w;
    }
    float acc[32];
    #pragma unroll
    for (int o = 0; o < 32; ++o) acc[o] = 0.0f;
    #pragma unroll
    for (int i = 0; i < 32; ++i) {
        float xi = x[i];
        #pragma unroll
        for (int o = 0; o < 32; ++o) acc[o] += xi * b2[i*32+o];
    }
    for (int k = 0; k < 32; ++k) {
        float hk = b1[k];
        #pragma unroll
        for (int j = 0; j < EDGE_DIM; ++j) hk += a[j] * W1[j*32 + k];
        hk = fmaxf(hk, 0.0f);
        const float* w = W2 + (size_t)k * 1024;
        #pragma unroll
        for (int i = 0; i < 32; ++i) {
            float c = hk * x[i];
            #pragma unroll
            for (int o = 0; o < 32; ++o) acc[o] += c * w[i*32+o];
        }
    }
    float4* m4 = reinterpret_cast<float4*>(msg + (size_t)e * 32);
    #pragma unroll
    for (int q = 0; q < 8; ++q) {
        float4 t;
        t.x = acc[q*4+0]; t.y = acc[q*4+1]; t.z = acc[q*4+2]; t.w = acc[q*4+3];
        m4[q] = t;
    }
}

// ===========================================================================

extern "C" void kernel_launch(void* const* d_in, const int* in_sizes, int n_in,
                              void* d_out, int out_size, void* d_ws, size_t ws_size,
                              hipStream_t stream)
{
    const float* x      = (const float*)d_in[0];
    const float* ea     = (const float*)d_in[1];
    const int*   ei     = (const int*)d_in[2];   // [2][E]
    const int*   batch  = (const int*)d_in[3];
    const float* en1_W1 = (const float*)d_in[4];
    const float* en1_b1 = (const float*)d_in[5];
    const float* en1_W2 = (const float*)d_in[6];
    const float* en1_b2 = (const float*)d_in[7];
    const float* root1  = (const float*)d_in[8];
    const float* bias1  = (const float*)d_in[9];
    const float* en2_W1 = (const float*)d_in[10];
    const float* en2_b1 = (const float*)d_in[11];
    const float* en2_W2 = (const float*)d_in[12];
    const float* en2_b2 = (const float*)d_in[13];
    const float* root2  = (const float*)d_in[14];
    const float* bias2  = (const float*)d_in[15];
    const float* fcW    = (const float*)d_in[16];
    const float* fcb    = (const float*)d_in[17];

    const int* srcs = ei;
    const int* tgts = ei + N_EDGES;

    dim3 eb(256), eg((N_EDGES + 255) / 256);
    dim3 gb(256), gg((N_NODES * 32 + 255) / 256);
    const int NBLK = (N_NODES + T_NODES - 1) / T_NODES;

    // ---- new-path workspace layout (words) ----
    // zeroed: [deg_t N][deg_s N][pool G*32][pcnt G]
    // then:   [start_t N+2][cur_t N][eid_t E][start_s N+2][cur_s N][eid_s E]
    //         [msg E*32][h1 N*32]        (pads keep msg 16B-aligned)
    size_t need_new = (size_t)2*N_NODES + N_GRAPHS*32 + N_GRAPHS
                    + 2*(N_NODES + 2) + 2*N_NODES + 2*(size_t)N_EDGES
                    + (size_t)N_EDGES*32 + (size_t)N_NODES*32;
    size_t need_old = (size_t)N_NODES + N_GRAPHS*32 + N_GRAPHS
                    + (N_NODES + 1) + N_NODES + N_EDGES
                    + (size_t)N_EDGES*32 + (size_t)N_NODES*32;

    if (ws_size >= need_new * sizeof(float)) {
        int*   deg_t   = (int*)d_ws;
        int*   deg_s   = deg_t + N_NODES;
        float* pool    = (float*)(deg_s + N_NODES);
        float* pcnt    = pool + (size_t)N_GRAPHS*32;
        int*   start_t = (int*)(pcnt + N_GRAPHS);
        int*   cur_t   = start_t + (N_NODES + 2);
        int*   eid_t   = cur_t + N_NODES;
        int*   start_s = eid_t + N_EDGES;
        int*   cur_s   = start_s + (N_NODES + 2);
        int*   eid_s   = cur_s + N_NODES;
        float* msg     = (float*)(eid_s + N_EDGES);
        float* h1      = msg + (size_t)N_EDGES*32;
        size_t zeroBytes = ((size_t)2*N_NODES + N_GRAPHS*32 + N_GRAPHS) * sizeof(float);

        hipMemsetAsync(d_ws, 0, zeroBytes, stream);

        build_deg2_kernel<<<eg, eb, 0, stream>>>(tgts, srcs, deg_t, deg_s);
        scan2_kernel<<<dim3(1), dim3(256), 0, stream>>>(deg_t, start_t, cur_t,
                                                        deg_s, start_s, cur_s);
        scatter2_kernel<<<eg, eb, 0, stream>>>(tgts, srcs, cur_t, cur_s, eid_t, eid_s);

        // conv1
        src_conv_kernel<<<dim3(NBLK), dim3(256), 0, stream>>>(
            x, ea, srcs, start_s, eid_s, en1_W1, en1_b1, en1_W2, en1_b2, msg);
        gather_update_kernel<<<gg, gb, 0, stream>>>(x, msg, start_t, eid_t, root1, bias1,
                                                    h1, nullptr, nullptr, nullptr);
        // conv2
        src_conv_kernel<<<dim3(NBLK), dim3(256), 0, stream>>>(
            h1, ea, srcs, start_s, eid_s, en2_W1, en2_b1, en2_W2, en2_b2, msg);
        gather_update_kernel<<<gg, gb, 0, stream>>>(h1, msg, start_t, eid_t, root2, bias2,
                                                    nullptr, batch, pool, pcnt);

        head_kernel<<<dim3(1), dim3(64), 0, stream>>>(pool, pcnt, fcW, fcb, (float*)d_out);
    } else {
        // round-2 proven fallback (per-edge fused, tgt-CSR only)
        int*   deg    = (int*)d_ws;
        float* pool   = (float*)(deg + N_NODES);
        float* pcnt   = pool + (size_t)N_GRAPHS*32;
        int*   start  = (int*)(pcnt + N_GRAPHS);
        int*   cursor = start + (N_NODES + 1);
        int*   eid    = cursor + N_NODES;
        float* msg    = (float*)(eid + N_EDGES);
        float* h1     = msg + (size_t)N_EDGES*32;
        size_t zeroBytes = ((size_t)N_NODES + N_GRAPHS*32 + N_GRAPHS) * sizeof(float);

        hipMemsetAsync(d_ws, 0, zeroBytes, stream);

        build_deg_kernel<<<eg, eb, 0, stream>>>(tgts, deg);
        scan_deg_kernel<<<dim3(1), dim3(256), 0, stream>>>(deg, start, cursor);
        scatter_edges_kernel<<<eg, eb, 0, stream>>>(tgts, cursor, eid);

        edge_msg_kernel<<<eg, eb, 0, stream>>>(x, ea, srcs,
                                               en1_W1, en1_b1, en1_W2, en1_b2, msg);
        gather_update_kernel<<<gg, gb, 0, stream>>>(x, msg, start, eid, root1, bias1,
                                                    h1, nullptr, nullptr, nullptr);
        edge_msg_kernel<<<eg, eb, 0, stream>>>(h1, ea, srcs,
                                               en2_W1, en2_b1, en2_W2, en2_b2, msg);
        gather_update_kernel<<<gg, gb, 0, stream>>>(h1, msg, start, eid, root2, bias2,
                                                    nullptr, batch, pool, pcnt);

        head_kernel<<<dim3(1), dim3(64), 0, stream>>>(pool, pcnt, fcW, fcb, (float*)d_out);
    }
}